// Round 6
// baseline (128.081 us; speedup 1.0000x reference)
//
#include <hip/hip_runtime.h>

typedef __bf16 bf16x8 __attribute__((ext_vector_type(8)));
typedef float f32x4 __attribute__((ext_vector_type(4)));

#define C_IN 128
#define HW_IN 3136      // 56*56 xt rows per image
#define K_OUT 256
#define OWP 56          // padded output width
#define M_REAL 3024     // 54*56 real rows per image
#define M_PAD 3072      // virtual per-image M: 16 tiles of 192
#define KG 1152         // 128*9
#define OUT_HW 2916     // 54*54
#define BN 192
#define NBLK 512        // 32 images * 16 tiles = exactly 2 waves of 256 CUs

// ws layout (bytes):
//   [0,4)          : absmax bits (uint)
//   [4096, 593920) : Bt bf16 [256][1152], kk = (r*3+s)*128 + c
//   [593920, ...)  : xt bf16 [n][hw:3136][c:128]  (25.69 MB, unchanged)

static __device__ __forceinline__ unsigned short f2bf(float f) {
  unsigned u = __float_as_uint(f);
  u += 0x7FFFu + ((u >> 16) & 1);   // RNE
  return (unsigned short)(u >> 16);
}

static __device__ __forceinline__ void gload16(const unsigned short* g, unsigned short* l) {
  __builtin_amdgcn_global_load_lds(
      (const __attribute__((address_space(1))) unsigned int*)g,
      (__attribute__((address_space(3))) unsigned int*)l, 16, 0, 0);
}

__global__ __launch_bounds__(256) void k_absmax(const float* __restrict__ w,
                                                unsigned* __restrict__ mx) {
  __shared__ float red[256];
  const int t = threadIdx.x;
  float v = fabsf(w[blockIdx.x * 256 + t]);
  red[t] = v;
  __syncthreads();
  for (int s = 128; s > 0; s >>= 1) {
    if (t < s) red[t] = fmaxf(red[t], red[t + s]);
    __syncthreads();
  }
  if (t == 0) atomicMax(mx, __float_as_uint(red[0]));
}

__global__ __launch_bounds__(256) void k_quant(const float* __restrict__ w,
                                               const unsigned* __restrict__ mx,
                                               unsigned short* __restrict__ bt) {
  const int idx = blockIdx.x * 256 + threadIdx.x;  // < 294912
  const float thr = 0.05f * __uint_as_float(*mx);
  const int k = idx / KG;
  const int j = idx - k * KG;
  const int rs = j >> 7;
  const int c = j & 127;
  const float v = w[k * KG + c * 9 + rs];
  float q = 0.f;
  if (v > thr) q = 1.f;
  else if (v < -thr) q = -1.f;
  bt[idx] = f2bf(q);
}

// x fp32 NCHW -> xt bf16 [n][hw][c], LDS tile transpose
__global__ __launch_bounds__(256) void k_xt(const float* __restrict__ x,
                                            unsigned short* __restrict__ xt) {
  __shared__ unsigned short tile[8192];
  const int n = blockIdx.x / 49;
  const int hw0 = (blockIdx.x - n * 49) * 64;
  const int t = threadIdx.x;
  const int j = t & 63;
  const int ci = t >> 6;
  const float* xp = x + (size_t)n * (C_IN * HW_IN) + hw0 + j;
#pragma unroll
  for (int it = 0; it < 32; ++it) {
    const int c = it * 4 + ci;
    tile[j * 128 + (c ^ j)] = f2bf(xp[(size_t)c * HW_IN]);
  }
  __syncthreads();
  const int jj = t >> 2;
  const int q = t & 3;
  unsigned short v[32] __attribute__((aligned(16)));
#pragma unroll
  for (int i = 0; i < 32; ++i)
    v[i] = tile[jj * 128 + ((q * 32 + i) ^ jj)];
  uint4* dst = (uint4*)(xt + (size_t)(n * HW_IN + hw0 + jj) * 128 + q * 32);
#pragma unroll
  for (int u = 0; u < 4; ++u)
    dst[u] = *(const uint4*)&v[u * 8];
}

// Conv GEMM, X-resident-in-LDS design:
//   Xr: block's full X panel (320 rows x 128 ch, 80KB) staged ONCE in prologue;
//       immutable -> X fragment reads need NO barriers for the whole K-loop.
//   As: A (weights) double-buffered 2x32KB, 4 gloads/thread/kt, counted vmcnt(4).
//   Per kt: 2 barriers, 1 vmcnt; X-read latency hides under the vmcnt wait.
__global__ __launch_bounds__(512) void k_conv(const unsigned short* __restrict__ xt,
                                              const unsigned short* __restrict__ bt,
                                              const float* __restrict__ bias,
                                              float* __restrict__ out) {
  __shared__ unsigned short Xr[40960];     // 320 rows x 128, 16B-chunk swizzled
  __shared__ unsigned short As[2][16384];  // [buf][256 rows x 64], 16B-chunk swizzled
  const int t = threadIdx.x;
  const int bid = blockIdx.x;
  const int spt = (bid & 7) * 64 + (bid >> 3);   // T1 bijective (512 = 8*64)
  const int img = spt >> 4;
  const int loc = (spt & 15) * BN;               // block-local padded-m base
  const int l = t & 63;
  const int wv = t >> 6;

  // ---- A staging: wave wv stages rows wv*32+u*8+(l>>3), u=0..3
  const int arl = l >> 3;                         // row-in-gload 0..7
  const unsigned short* abase = bt + (size_t)(wv * 32 + arl) * KG
                              + (((l & 7) ^ (arl & 7)) << 3);   // pre-swizzled chunk
  const int adst = wv * 2048;                     // + u*512 (shorts)

  // ---- fragment setup
  const int wm = wv >> 1;   // 0..3: kch rows wm*64..+63
  const int wn = wv & 1;    // 0..1: spatial cols wn*96..+95
  const int lr = l & 15;
  const int hh = l >> 4;
  const int asw = ((hh ^ (lr & 7)) << 3);         // A phys chunk, ks0 (ks1: ^32)

  f32x4 acc[4][6];
#pragma unroll
  for (int f = 0; f < 4; ++f)
#pragma unroll
    for (int fn = 0; fn < 6; ++fn)
      acc[f][fn] = (f32x4){0.f, 0.f, 0.f, 0.f};

  // ---- prologue: stage X panel (10 gloads) + A kt0 (4 gloads), drain, barrier
  {
#pragma unroll
    for (int u = 0; u < 10; ++u) {
      const int Lr = wv * 40 + u * 4 + (l >> 4);          // LDS-local row 0..319
      int grow = loc + Lr;                                 // global row in image
      if (grow > HW_IN - 1) grow = HW_IN - 1;              // clamp (masked outputs only)
      const unsigned short* src = xt + ((size_t)img * HW_IN + grow) * 128
                                + (((l & 15) ^ (Lr & 7)) << 3);
      gload16(src, &Xr[(wv * 40 + u * 4) * 128]);
    }
#pragma unroll
    for (int u = 0; u < 4; ++u)
      gload16(abase + (size_t)u * 8 * KG, &As[0][adst + u * 512]);
    asm volatile("s_waitcnt vmcnt(0)" ::: "memory");
    __builtin_amdgcn_s_barrier();
    __builtin_amdgcn_sched_barrier(0);
  }

  auto body = [&](int kt, int b, int ob, bool LAST) __attribute__((always_inline)) {
    const int rs = kt >> 1;
    const int chalf = kt & 1;
    const int rd = rs / 3;
    const int rm = rs - rd * 3;
    const int roff = rd * 56 + rm;
    __builtin_amdgcn_s_barrier();          // all waves' reads of As[ob] (kt-1) done
    __builtin_amdgcn_sched_barrier(0);
    if (!LAST) {
      const int nko = (kt + 1) << 6;
#pragma unroll
      for (int u = 0; u < 4; ++u)
        gload16(abase + (size_t)u * 8 * KG + nko, &As[ob][adst + u * 512]);
    }
    __builtin_amdgcn_sched_barrier(0);
    // X fragments: immutable LDS, no sync — latency hides under vmcnt wait
    bf16x8 xf0[6], xf1[6];
#pragma unroll
    for (int fn = 0; fn < 6; ++fn) {
      const int rx = wn * 96 + fn * 16 + lr + roff;
      const int rb = rx * 128;
      const int k8 = rx & 7;
      xf0[fn] = *(const bf16x8*)&Xr[rb + (((chalf * 8 + hh) ^ k8) << 3)];
      xf1[fn] = *(const bf16x8*)&Xr[rb + (((chalf * 8 + 4 + hh) ^ k8) << 3)];
    }
    __builtin_amdgcn_sched_barrier(0);
    if (!LAST) asm volatile("s_waitcnt vmcnt(4)" ::: "memory");   // kt's A landed
    else       asm volatile("s_waitcnt vmcnt(0)" ::: "memory");
    __builtin_amdgcn_s_barrier();          // all waves' A visible
    __builtin_amdgcn_sched_barrier(0);
    bf16x8 af0[4], af1[4];
#pragma unroll
    for (int f = 0; f < 4; ++f) {
      const int ar = (wm * 64 + f * 16 + lr) << 6;
      af0[f] = *(const bf16x8*)&As[b][ar + asw];
      af1[f] = *(const bf16x8*)&As[b][ar + (asw ^ 32)];
    }
    __builtin_amdgcn_s_setprio(1);
#pragma unroll
    for (int f = 0; f < 4; ++f)
#pragma unroll
      for (int fn = 0; fn < 6; ++fn)
        acc[f][fn] = __builtin_amdgcn_mfma_f32_16x16x32_bf16(af0[f], xf0[fn], acc[f][fn], 0, 0, 0);
    __builtin_amdgcn_s_setprio(0);
    __builtin_amdgcn_s_setprio(1);
#pragma unroll
    for (int f = 0; f < 4; ++f)
#pragma unroll
      for (int fn = 0; fn < 6; ++fn)
        acc[f][fn] = __builtin_amdgcn_mfma_f32_16x16x32_bf16(af1[f], xf1[fn], acc[f][fn], 0, 0, 0);
    __builtin_amdgcn_s_setprio(0);
  };

  for (int kp = 0; kp < 8; ++kp) {
    body(2 * kp, 0, 1, false);
    body(2 * kp + 1, 1, 0, false);
  }
  body(16, 0, 1, false);
  body(17, 1, 0, true);

  // ---- epilogue: D row=(hh*4+rg) -> kch; col=lr -> spatial
  float bv[4][4];
#pragma unroll
  for (int f = 0; f < 4; ++f)
#pragma unroll
    for (int rg = 0; rg < 4; ++rg)
      bv[f][rg] = bias[wm * 64 + f * 16 + hh * 4 + rg];

#pragma unroll
  for (int fn = 0; fn < 6; ++fn) {
    const int mv = loc + wn * 96 + fn * 16 + lr;   // block-local padded m
    const int oh = mv / OWP;
    const int ow = mv - oh * OWP;
    if (mv < M_REAL && ow < 54) {
      float* op = out + (size_t)img * (K_OUT * OUT_HW) + oh * 54 + ow;
#pragma unroll
      for (int f = 0; f < 4; ++f) {
        const int kbase = wm * 64 + f * 16 + hh * 4;
#pragma unroll
        for (int rg = 0; rg < 4; ++rg)
          op[(size_t)(kbase + rg) * OUT_HW] = acc[f][fn][rg] + bv[f][rg];
      }
    }
  }
}

extern "C" void kernel_launch(void* const* d_in, const int* in_sizes, int n_in,
                              void* d_out, int out_size, void* d_ws, size_t ws_size,
                              hipStream_t stream) {
  const float* x = (const float*)d_in[0];
  const float* w = (const float*)d_in[1];
  const float* bias = (const float*)d_in[2];
  float* out = (float*)d_out;
  unsigned char* ws = (unsigned char*)d_ws;
  unsigned* mx = (unsigned*)ws;
  unsigned short* bt = (unsigned short*)(ws + 4096);
  unsigned short* xt = (unsigned short*)(ws + 593920);

  hipMemsetAsync(mx, 0, 4, stream);
  k_absmax<<<1152, 256, 0, stream>>>(w, mx);
  k_quant<<<1152, 256, 0, stream>>>(w, mx, bt);
  k_xt<<<32 * 49, 256, 0, stream>>>(x, xt);
  k_conv<<<NBLK, 512, 0, stream>>>(xt, bt, bias, out);
}

// Round 7
// 108.009 us; speedup vs baseline: 1.1858x; 1.1858x over previous
//
#include <hip/hip_runtime.h>

typedef __bf16 bf16x8 __attribute__((ext_vector_type(8)));
typedef float f32x4 __attribute__((ext_vector_type(4)));

#define C_IN 128
#define HW_IN 3136      // 56*56 xt rows per image
#define K_OUT 256
#define OWP 56          // padded output width
#define M_PER_IMG 3024  // 54*56 padded-m rows per image
#define KG 1152         // 128*9
#define OUT_HW 2916     // 54*54
#define NBLK 3024       // 756 spatial tiles x 4 kch tiles = 8*378

// ws layout (bytes):
//   [0,4)          : absmax bits (uint)
//   [4096, 593920) : Bt bf16 [256][1152], kk = (r*3+s)*128 + c
//   [593920, ...)  : xt bf16 [n][hw:3136][c:128] + >=1KB tail pad (OOB taps of
//                    masked output rows read past the last image; pad absorbs)

static __device__ __forceinline__ unsigned short f2bf(float f) {
  unsigned u = __float_as_uint(f);
  u += 0x7FFFu + ((u >> 16) & 1);   // RNE
  return (unsigned short)(u >> 16);
}

static __device__ __forceinline__ void gload16(const unsigned short* g, unsigned short* l) {
  __builtin_amdgcn_global_load_lds(
      (const __attribute__((address_space(1))) unsigned int*)g,
      (__attribute__((address_space(3))) unsigned int*)l, 16, 0, 0);
}

__global__ __launch_bounds__(256) void k_absmax(const float* __restrict__ w,
                                                unsigned* __restrict__ mx) {
  __shared__ float red[256];
  const int t = threadIdx.x;
  float v = fabsf(w[blockIdx.x * 256 + t]);
  red[t] = v;
  __syncthreads();
  for (int s = 128; s > 0; s >>= 1) {
    if (t < s) red[t] = fmaxf(red[t], red[t + s]);
    __syncthreads();
  }
  if (t == 0) atomicMax(mx, __float_as_uint(red[0]));
}

__global__ __launch_bounds__(256) void k_quant(const float* __restrict__ w,
                                               const unsigned* __restrict__ mx,
                                               unsigned short* __restrict__ bt) {
  const int idx = blockIdx.x * 256 + threadIdx.x;  // < 294912
  const float thr = 0.05f * __uint_as_float(*mx);
  const int k = idx / KG;
  const int j = idx - k * KG;
  const int rs = j >> 7;
  const int c = j & 127;
  const float v = w[k * KG + c * 9 + rs];
  float q = 0.f;
  if (v > thr) q = 1.f;
  else if (v < -thr) q = -1.f;
  bt[idx] = f2bf(q);
}

// x fp32 NCHW -> xt bf16 [n][hw][c], LDS tile transpose
__global__ __launch_bounds__(256) void k_xt(const float* __restrict__ x,
                                            unsigned short* __restrict__ xt) {
  __shared__ unsigned short tile[8192];
  const int n = blockIdx.x / 49;
  const int hw0 = (blockIdx.x - n * 49) * 64;
  const int t = threadIdx.x;
  const int j = t & 63;
  const int ci = t >> 6;
  const float* xp = x + (size_t)n * (C_IN * HW_IN) + hw0 + j;
#pragma unroll
  for (int it = 0; it < 32; ++it) {
    const int c = it * 4 + ci;
    tile[j * 128 + (c ^ j)] = f2bf(xp[(size_t)c * HW_IN]);
  }
  __syncthreads();
  const int jj = t >> 2;
  const int q = t & 3;
  unsigned short v[32] __attribute__((aligned(16)));
#pragma unroll
  for (int i = 0; i < 32; ++i)
    v[i] = tile[jj * 128 + ((q * 32 + i) ^ jj)];
  uint4* dst = (uint4*)(xt + (size_t)(n * HW_IN + hw0 + jj) * 128 + q * 32);
#pragma unroll
  for (int u = 0; u < 4; ++u)
    dst[u] = *(const uint4*)&v[u * 8];
}

// Conv GEMM, register-lean high-TLP config:
//   tile 64 kch x 128 sp x BK=64, 4 waves (wave = 64x32), acc = 8 f32x4.
//   Target >=4 blocks/CU so independent blocks hide each other's load drains
//   (m114 inter-block overlap). Single 24KB LDS buffer, R2-style minimal loop:
//   bar -> issue 6 gloads -> vmcnt(0) -> bar -> 12 ds_read + 16 MFMA.
__global__ __launch_bounds__(256, 4) void k_conv(const unsigned short* __restrict__ xt,
                                                 const unsigned short* __restrict__ bt,
                                                 const float* __restrict__ bias,
                                                 float* __restrict__ out) {
  __shared__ unsigned short As[4096];   // 64 rows x 64 kk, 8-chunk XOR swizzle
  __shared__ unsigned short Xs[8192];   // 128 rows x 64 kk, 8-chunk XOR swizzle
  const int t = threadIdx.x;
  // T1 XCD swizzle (3024 = 8*378); consecutive g on one XCD: 4 kch tiles per
  // spatial tile then spt+1 -> strong per-XCD L2 locality on xt.
  const int g = (blockIdx.x & 7) * 378 + (blockIdx.x >> 3);
  const int kcht = g & 3;    // 0..3 kch tile
  const int spt = g >> 2;    // 0..755 spatial tile

  // ---- staging: thread t -> row srow (0..31), chunk sch (0..7); pre-swizzled src
  const int srow = t >> 3;
  const int sch = t & 7;
  const int ssw = ((sch ^ (srow & 7)) << 3);   // shorts
  const unsigned short* asrc0 = bt + (size_t)(kcht * 64 + srow) * KG + ssw;
  const unsigned short* asrc1 = asrc0 + (size_t)32 * KG;   // (srow+32)&7 == srow&7
  const unsigned short* xsrc[4];
#pragma unroll
  for (int q = 0; q < 4; ++q) {
    const int m = spt * 128 + q * 32 + srow;    // q*32 keeps (row&7) invariant
    xsrc[q] = xt + (size_t)(m + 112 * (m / M_PER_IMG)) * 128 + ssw;
  }
  const int wv = t >> 6;
  const int wvb = wv * 512;   // wave-uniform dest base (shorts)

  // ---- fragment setup
  const int l = t & 63;
  const int lr = l & 15;
  const int hh = l >> 4;
  const int lsw = lr & 7;

  f32x4 acc[4][2];
#pragma unroll
  for (int f = 0; f < 4; ++f)
#pragma unroll
    for (int fx = 0; fx < 2; ++fx)
      acc[f][fx] = (f32x4){0.f, 0.f, 0.f, 0.f};

  for (int kt = 0; kt < 18; ++kt) {
    const int rs = kt >> 1;
    const int rd = rs / 3;
    const int rm = rs - rd * 3;
    const int xoff = (rd * 56 + rm) * 128 + ((kt & 1) << 6);
    const int aoff = kt << 6;
    __builtin_amdgcn_s_barrier();            // all waves done reading prev tile
    gload16(asrc0 + aoff, &As[wvb]);
    gload16(asrc1 + aoff, &As[2048 + wvb]);
    gload16(xsrc[0] + xoff, &Xs[wvb]);
    gload16(xsrc[1] + xoff, &Xs[2048 + wvb]);
    gload16(xsrc[2] + xoff, &Xs[4096 + wvb]);
    gload16(xsrc[3] + xoff, &Xs[6144 + wvb]);
    asm volatile("s_waitcnt vmcnt(0)" ::: "memory");
    __builtin_amdgcn_s_barrier();            // staged data visible
    __builtin_amdgcn_sched_barrier(0);       // pin ds_reads below barrier
#pragma unroll
    for (int ks = 0; ks < 2; ++ks) {
      const int ch = (((ks << 2) + hh) ^ lsw) << 3;
      bf16x8 af[4], xf[2];
#pragma unroll
      for (int f = 0; f < 4; ++f)
        af[f] = *(const bf16x8*)&As[((f * 16 + lr) << 6) + ch];
#pragma unroll
      for (int fx = 0; fx < 2; ++fx)
        xf[fx] = *(const bf16x8*)&Xs[((wv * 32 + fx * 16 + lr) << 6) + ch];
      __builtin_amdgcn_s_setprio(1);
#pragma unroll
      for (int f = 0; f < 4; ++f)
#pragma unroll
        for (int fx = 0; fx < 2; ++fx)
          acc[f][fx] = __builtin_amdgcn_mfma_f32_16x16x32_bf16(af[f], xf[fx], acc[f][fx], 0, 0, 0);
      __builtin_amdgcn_s_setprio(0);
    }
  }

  // ---- epilogue: D row=(hh*4+rg) -> kch; col=lr -> spatial
  float bv[4][4];
#pragma unroll
  for (int f = 0; f < 4; ++f)
#pragma unroll
    for (int rg = 0; rg < 4; ++rg)
      bv[f][rg] = bias[kcht * 64 + f * 16 + hh * 4 + rg];

#pragma unroll
  for (int fx = 0; fx < 2; ++fx) {
    const int m = spt * 128 + wv * 32 + fx * 16 + lr;
    const int ni = m / M_PER_IMG;
    const int rem = m - ni * M_PER_IMG;
    const int oh = rem / OWP;
    const int ow = rem - oh * OWP;
    if (ow < 54) {
      float* op = out + (size_t)ni * (K_OUT * OUT_HW) + oh * 54 + ow;
#pragma unroll
      for (int f = 0; f < 4; ++f) {
        const int kbase = kcht * 64 + f * 16 + hh * 4;
#pragma unroll
        for (int rg = 0; rg < 4; ++rg)
          op[(size_t)(kbase + rg) * OUT_HW] = acc[f][fx][rg] + bv[f][rg];
      }
    }
  }
}

extern "C" void kernel_launch(void* const* d_in, const int* in_sizes, int n_in,
                              void* d_out, int out_size, void* d_ws, size_t ws_size,
                              hipStream_t stream) {
  const float* x = (const float*)d_in[0];
  const float* w = (const float*)d_in[1];
  const float* bias = (const float*)d_in[2];
  float* out = (float*)d_out;
  unsigned char* ws = (unsigned char*)d_ws;
  unsigned* mx = (unsigned*)ws;
  unsigned short* bt = (unsigned short*)(ws + 4096);
  unsigned short* xt = (unsigned short*)(ws + 593920);

  hipMemsetAsync(mx, 0, 4, stream);
  k_absmax<<<1152, 256, 0, stream>>>(w, mx);
  k_quant<<<1152, 256, 0, stream>>>(w, mx, bt);
  k_xt<<<32 * 49, 256, 0, stream>>>(x, xt);
  k_conv<<<NBLK, 256, 0, stream>>>(xt, bt, bias, out);
}